// Round 17
// baseline (2026.900 us; speedup 1.0000x reference)
//
#include <hip/hip_runtime.h>

#define B_ 64
#define T_ 256
#define LC_ 16
#define CV_ 128
#define CE_ 100
#define WE_ 300
#define CH_ 100
#define WH_ 300
#define NTAG 20
#define START_ 18
#define STOP_ 19
#define NEG_ -10000.0f
#define NSEQ (B_*T_)          // 16384
#define KFP 416               // padded feat row (400 data + 16 zero)
#define NW_ 25                // workgroups per direction in k_word2
#define UH_ 12                // hidden units per workgroup (25*12=300)
#define ROW_DW 164            // dwords per batch row in hh (= h_s LDS row: 328 bf16)
#define SLOT_DW (64*ROW_DW)   // 10,496 dwords per slot
#define HH_DW (2*257*SLOT_DW) // 5,394,944 dwords total
#define FLAGS_N 512           // 2 dirs x 256 ints (200 used per dir)
#define ZBLK ((HH_DW + FLAGS_N + 255)/256)

typedef unsigned short ushort_t;
typedef __attribute__((ext_vector_type(8))) short bf16x8;
typedef __attribute__((ext_vector_type(4))) float f32x4;
union BF8 { bf16x8 v; ushort_t u[8]; };

__device__ inline float bf2f(ushort_t u){ return __uint_as_float(((unsigned int)u)<<16); }
__device__ inline ushort_t f2bf(float f){
  unsigned int x = __float_as_uint(f);
  unsigned int r = (x + 0x7fffu + ((x>>16)&1u)) >> 16;
  return (ushort_t)r;
}
__device__ inline float sigm(float x){ return 1.f/(1.f+__expf(-x)); }
__device__ inline float ftanh(float x){
  float ax = fabsf(x);
  float e = __expf(-2.f*ax);
  float t = (1.f-e)/(1.f+e);
  return copysignf(t, x);
}
// async global->LDS 16B DMA; aux=17 (SC0|SC1: cache-bypass, MALL-coherent) for h
__device__ inline void gload16_byp(const unsigned* g, unsigned* l){
  __builtin_amdgcn_global_load_lds((const __attribute__((address_space(1))) unsigned*)g,
                                   (__attribute__((address_space(3))) unsigned*)l, 16, 0, 17);
}
// cached variant for read-only feat
__device__ inline void gload16(const unsigned* g, unsigned* l){
  __builtin_amdgcn_global_load_lds((const __attribute__((address_space(1))) unsigned*)g,
                                   (__attribute__((address_space(3))) unsigned*)l, 16, 0, 0);
}
// L1/L2-bypass flag quad load (MALL-served, re-pollable)
__device__ inline int4 ld_flag4(const int* p){
  int4 r;
  asm volatile("global_load_dwordx4 %0, %1, off sc0 sc1\n\ts_waitcnt vmcnt(0)"
               : "=v"(r) : "v"(p) : "memory");
  return r;
}

// ---------- 0. prep: [0..ZBLK) zero whole hh + flags; [ZBLK..+200) char gate table
__global__ __launch_bounds__(256) void k_prep(unsigned int* __restrict__ hh, int* __restrict__ flags,
    const float* __restrict__ cemb, const float* __restrict__ cWih,
    const float* __restrict__ cbih, const float* __restrict__ cbhh, float* __restrict__ Ec_t){
  int bid = blockIdx.x;
  if (bid < ZBLK){
    size_t idx = (size_t)bid*256 + threadIdx.x;
    if (idx < HH_DW) hh[idx] = 0u;
    else if (idx < HH_DW + FLAGS_N) flags[idx - HH_DW] = 0;
  } else {
    int idx = (bid - ZBLK)*256 + threadIdx.x;    // 51200 = 400*128
    int r = idx >> 7, c = idx & 127;
    float a = cbih[r] + cbhh[r];
    for (int k=0;k<CE_;++k) a += cemb[c*CE_+k]*cWih[r*CE_+k];
    Ec_t[c*400 + r] = a;
  }
}

// ---------- 2. char LSTM (MFMA): 64 seqs/WG, 4 waves; writes h DIRECTLY into feat char cols
__global__ __launch_bounds__(256) void k_char(const float* __restrict__ Ec_t,
    const float* __restrict__ Whh, const int* __restrict__ char_x,
    ushort_t* __restrict__ feat){
  extern __shared__ char csm[];
  ushort_t* h_lds = (ushort_t*)csm;              // [64][132] bf16 = 16,896 B
  float*    g_lds = (float*)(csm + 64*132*2);    // [64][401] f32  = 102,656 B
  const int tid  = threadIdx.x;
  const int lane = tid & 63;
  const int w    = tid >> 6;                     // 4 waves
  const int tb   = w*6;                          // n-tile base (w3 also does tile 24)
  bf16x8 Bf[7][4];
  {
    int ntile = (w==3) ? 7 : 6;
    for (int tt=0; tt<ntile; ++tt){
      int r = (tb+tt)*16 + (lane & 15);
      #pragma unroll
      for (int ks=0; ks<4; ++ks){
        BF8 tmp;
        #pragma unroll
        for (int j=0; j<8; ++j){
          int k = 32*ks + 8*(lane>>4) + j;
          tmp.u[j] = (k < CH_) ? f2bf(Whh[(size_t)r*CH_ + k]) : (ushort_t)0;
        }
        Bf[tt][ks] = tmp.v;
      }
    }
  }
  for (int i=tid; i<64*132; i+=256) h_lds[i] = 0;
  const int seq_l = tid & 63;
  const int us    = tid >> 6;
  const int seqg  = blockIdx.x*64 + seq_l;
  const int u0    = us*25;
  float c_r[25], h_r[25];
  #pragma unroll
  for (int j=0;j<25;++j){ c_r[j]=0.f; h_r[j]=0.f; }
  const int* cx = char_x + (size_t)seqg*LC_;
  __syncthreads();
  #pragma unroll 1
  for (int t=0; t<LC_; ++t){
    #pragma unroll
    for (int m=0; m<4; ++m){
      int abase = (16*m + (lane&15))*132 + 8*(lane>>4);
      bf16x8 a0 = *(const bf16x8*)(h_lds + abase);
      bf16x8 a1 = *(const bf16x8*)(h_lds + abase + 32);
      bf16x8 a2 = *(const bf16x8*)(h_lds + abase + 64);
      bf16x8 a3 = *(const bf16x8*)(h_lds + abase + 96);
      int rw = 16*m + 4*(lane>>4);
      #pragma unroll
      for (int tt=0; tt<6; ++tt){
        f32x4 acc = {0,0,0,0};
        acc = __builtin_amdgcn_mfma_f32_16x16x32_bf16(a0, Bf[tt][0], acc, 0,0,0);
        acc = __builtin_amdgcn_mfma_f32_16x16x32_bf16(a1, Bf[tt][1], acc, 0,0,0);
        acc = __builtin_amdgcn_mfma_f32_16x16x32_bf16(a2, Bf[tt][2], acc, 0,0,0);
        acc = __builtin_amdgcn_mfma_f32_16x16x32_bf16(a3, Bf[tt][3], acc, 0,0,0);
        int col = (tb+tt)*16 + (lane&15);
        #pragma unroll
        for (int r4=0;r4<4;++r4) g_lds[(rw+r4)*401 + col] = acc[r4];
      }
      if (w == 3){
        f32x4 acc = {0,0,0,0};
        acc = __builtin_amdgcn_mfma_f32_16x16x32_bf16(a0, Bf[6][0], acc, 0,0,0);
        acc = __builtin_amdgcn_mfma_f32_16x16x32_bf16(a1, Bf[6][1], acc, 0,0,0);
        acc = __builtin_amdgcn_mfma_f32_16x16x32_bf16(a2, Bf[6][2], acc, 0,0,0);
        acc = __builtin_amdgcn_mfma_f32_16x16x32_bf16(a3, Bf[6][3], acc, 0,0,0);
        int col = 24*16 + (lane&15);
        #pragma unroll
        for (int r4=0;r4<4;++r4) g_lds[(rw+r4)*401 + col] = acc[r4];
      }
    }
    int ch = cx[t];
    __syncthreads();
    {
      const float* ec = Ec_t + (size_t)ch*400;
      const float* gr = g_lds + seq_l*401;
      #pragma unroll
      for (int j=0;j<25;++j){
        int u = u0 + j;
        float gi = gr[u        ] + ec[u        ];
        float gf = gr[100 + u  ] + ec[100 + u  ];
        float gg = gr[200 + u  ] + ec[200 + u  ];
        float go = gr[300 + u  ] + ec[300 + u  ];
        float I = sigm(gi), F = sigm(gf), G = ftanh(gg), O = sigm(go);
        float cn = F*c_r[j] + I*G;
        float hn = O*ftanh(cn);
        if (ch > 0){ c_r[j] = cn; h_r[j] = hn; }
        h_lds[seq_l*132 + u] = f2bf(h_r[j]);
      }
    }
    __syncthreads();
  }
  {
    int bb = seqg >> 8, tt2 = seqg & 255;
    ushort_t* dst = feat + (size_t)(tt2*64 + bb)*KFP + WE_ + u0;
    #pragma unroll
    for (int j=0;j<25;++j) dst[j] = f2bf(h_r[j]);
  }
}

// ---------- 3. feat builder: cols 0..299 = wemb[word_x]; cols 300..415 zeroed
__global__ __launch_bounds__(256) void k_feat(const int* __restrict__ word_x,
    const float* __restrict__ wemb, ushort_t* __restrict__ feat){
  int gid = blockIdx.x*256 + threadIdx.x;      // 16384*104 groups of 4 cols
  int rf = gid / 104;                          // rf = t*64 + b
  int j4 = gid - rf*104;
  int k = 4*j4;
  int t = rf >> 6, b = rf & 63;
  ushort4 u = make_ushort4(0,0,0,0);
  if (k < WE_){
    int seq = b*T_ + t;
    int wid = word_x[seq];
    float4 v = *(const float4*)&wemb[(size_t)wid*WE_ + k];
    u.x=f2bf(v.x); u.y=f2bf(v.y); u.z=f2bf(v.z); u.w=f2bf(v.w);
  }
  *(ushort4*)&feat[(size_t)rf*KFP + k] = u;
}

// ---------- 4. word LSTM: all-DMA staging, double-buffered feat, g_s overlays f_cur,
//              per-wave flags (no end barrier), busy-poll (no sleep).
__global__ __launch_bounds__(512, 2) void k_word2(
    const ushort_t* __restrict__ feat, unsigned int* __restrict__ hhd,
    const float* __restrict__ fWih, const float* __restrict__ fWhh,
    const float* __restrict__ fbih, const float* __restrict__ fbhh,
    const float* __restrict__ bWih, const float* __restrict__ bWhh,
    const float* __restrict__ bbih, const float* __restrict__ bbhh,
    const int* __restrict__ word_x, int* __restrict__ flags){
  extern __shared__ char smem[];
  ushort_t* h_s    = (ushort_t*)smem;                          // [64][328] = 41,984 B
  ushort_t* f_sb0  = (ushort_t*)(smem + 41984);                // [64][416] = 53,248 B
  ushort_t* f_sb1  = (ushort_t*)(smem + 41984 + 53248);        // [64][416] = 53,248 B
  unsigned* mask_s = (unsigned*)(smem + 41984 + 106496);       // [64][8]   =  2,048 B
  const int tid  = threadIdx.x;
  const int lane = tid & 63;
  const int w    = tid >> 6;         // 8 waves
  const int dir  = blockIdx.x & 1;
  const int g    = blockIdx.x >> 1;  // 0..24
  const int u0   = g * UH_;
  const int tm   = w & 3;            // m-tile (batch 16-row group)
  const int grp  = w >> 2;           // 0: n-tiles {0,1}; 1: n-tile {2}
  const bool two = (grp == 0);
  const int tnb  = grp ? 2 : 0;
  const float* Wih = dir ? bWih : fWih;
  const float* Whh = dir ? bWhh : fWhh;
  const float* bi  = dir ? bbih : fbih;
  const float* bh  = dir ? bbhh : fbhh;
  int* myflags = flags + dir*256;

  // ---- persistent B fragments (W_ih: 13 k-slabs; W_hh: 10 k-slabs)
  bf16x8 B2[2][13], B1[2][10];
  {
    const int kb = 8*(lane >> 4);
    #pragma unroll
    for (int ti=0; ti<2; ++ti){
      if (ti == 0 || two){
        int nl = 16*(tnb+ti) + (lane & 15);
        int r  = (nl & 3)*WH_ + u0 + (nl >> 2);   // gate q*300 + unit
        #pragma unroll
        for (int kk=0; kk<13; ++kk){
          BF8 tmp;
          #pragma unroll
          for (int j=0; j<8; ++j){
            int k = 32*kk + kb + j;
            tmp.u[j] = (k < 400) ? f2bf(Wih[(size_t)r*400 + k]) : (ushort_t)0;
          }
          B2[ti][kk] = tmp.v;
        }
        #pragma unroll
        for (int kk=0; kk<10; ++kk){
          BF8 tmp;
          #pragma unroll
          for (int j=0; j<8; ++j){
            int k = 32*kk + kb + j;
            tmp.u[j] = (k < WH_) ? f2bf(Whh[(size_t)r*WH_ + k]) : (ushort_t)0;
          }
          B1[ti][kk] = tmp.v;
        }
      }
    }
  }
  // ---- build word-mask bitmap: mask_s[b][t>>5] bit (t&31)
  if (tid < 512){
    int row = tid >> 3, dw = tid & 7;
    const int* wp = word_x + row*T_ + dw*32;
    unsigned bits = 0u;
    #pragma unroll
    for (int j4=0; j4<8; ++j4){
      int4 v = *(const int4*)(wp + 4*j4);
      bits |= (v.x>0 ? 1u:0u) << (4*j4);
      bits |= (v.y>0 ? 1u:0u) << (4*j4+1);
      bits |= (v.z>0 ? 1u:0u) << (4*j4+2);
      bits |= (v.w>0 ? 1u:0u) << (4*j4+3);
    }
    mask_s[row*8 + dw] = bits;
  }

  // ---- update threads: tid<384: m_u = tid&63, up = tid>>6 (units u0+2up, u0+2up+1)
  const int m_u = tid & 63;
  const int up  = tid >> 6;          // 0..5 for update threads
  float4 bias_a = {0,0,0,0}, bias_b = {0,0,0,0};
  if (tid < 384){
    int u = u0 + 2*up;
    bias_a.x = bi[0*WH_+u] + bh[0*WH_+u];
    bias_a.y = bi[1*WH_+u] + bh[1*WH_+u];
    bias_a.z = bi[2*WH_+u] + bh[2*WH_+u];
    bias_a.w = bi[3*WH_+u] + bh[3*WH_+u];
    bias_b.x = bi[0*WH_+u+1] + bh[0*WH_+u+1];
    bias_b.y = bi[1*WH_+u+1] + bh[1*WH_+u+1];
    bias_b.z = bi[2*WH_+u+1] + bh[2*WH_+u+1];
    bias_b.w = bi[3*WH_+u+1] + bh[3*WH_+u+1];
  }
  float c_a=0.f, h_a=0.f, c_b=0.f, h_b=0.f;
  const int arow_f = (16*tm + (lane&15))*KFP + 8*(lane>>4);
  const int arow_h = (16*tm + (lane&15))*328 + 8*(lane>>4);
  unsigned* h_sd = (unsigned*)h_s;

  // ---- prologue: DMA feat(first t) into buffer 0 (3328 x 16B)
  {
    int t0 = dir ? (T_-1) : 0;
    const unsigned* fsrc = (const unsigned*)(feat + (size_t)t0*64*KFP);
    unsigned* fdl = (unsigned*)f_sb0;
    #pragma unroll
    for (int i=0;i<7;++i){
      int idx = tid + 512*i;
      if (i < 6 || idx < 3328) gload16(fsrc + 4*idx, fdl + 4*idx);
    }
  }
  asm volatile("s_waitcnt vmcnt(0)" ::: "memory");
  __syncthreads();

  #pragma unroll 1
  for (int s=0; s<T_; ++s){
    int t = dir ? (T_-1-s) : s;
    const ushort_t* f_cur = (s & 1) ? f_sb1 : f_sb0;
    float* g_s = (float*)f_cur;          // overlay: valid after all f_cur MFMA reads
    // -- busy-poll all 200 per-wave flags (wave 0; lanes cover 256 ints)
    if (w == 0 && s > 0){
      const int* fp = myflags + lane*4;
      for (int it=0; it<4000000; ++it){
        int4 v = ld_flag4(fp);
        int mn = min(min(v.x, v.y), min(v.z, v.w));
        if (lane >= 50) mn = 0x7fffffff;
        if (__all(mn >= s)) break;
      }
    }
    __syncthreads();   // B1: h(s) globally published (all waves' flags >= s)
    // -- issue async h(s) DMA: 2624 x 16B (global layout == LDS layout, pads zero)
    {
      const unsigned* hsrc = hhd + (size_t)(dir*257 + s)*SLOT_DW;
      #pragma unroll
      for (int i=0;i<6;++i){
        int idx = tid + 512*i;
        if (i < 5 || idx < 2624) gload16_byp(hsrc + 4*idx, h_sd + 4*idx);
      }
    }
    // -- feat MFMAs overlap the h DMA
    f32x4 acc0a = {0,0,0,0}, acc0b = {0,0,0,0}, acc1a = {0,0,0,0}, acc1b = {0,0,0,0};
    #pragma unroll
    for (int kk=0; kk<13; ++kk){
      bf16x8 a = *(const bf16x8*)(f_cur + arow_f + 32*kk);
      if (kk & 1){
        acc0b = __builtin_amdgcn_mfma_f32_16x16x32_bf16(a, B2[0][kk], acc0b, 0,0,0);
        if (two) acc1b = __builtin_amdgcn_mfma_f32_16x16x32_bf16(a, B2[1][kk], acc1b, 0,0,0);
      } else {
        acc0a = __builtin_amdgcn_mfma_f32_16x16x32_bf16(a, B2[0][kk], acc0a, 0,0,0);
        if (two) acc1a = __builtin_amdgcn_mfma_f32_16x16x32_bf16(a, B2[1][kk], acc1a, 0,0,0);
      }
    }
    asm volatile("s_waitcnt vmcnt(0)" ::: "memory");   // h DMA landed (this wave)
    __syncthreads();   // B2: all waves' h DMA landed; all f_cur reads complete
    // -- issue feat(s+1) DMA into the other buffer (drained by per-wave vmcnt below)
    if (s + 1 < T_){
      int tn = dir ? (T_-2-s) : (s+1);
      const unsigned* fsrc = (const unsigned*)(feat + (size_t)tn*64*KFP);
      unsigned* fdl = (unsigned*)((s & 1) ? f_sb0 : f_sb1);
      #pragma unroll
      for (int i=0;i<7;++i){
        int idx = tid + 512*i;
        if (i < 6 || idx < 3328) gload16(fsrc + 4*idx, fdl + 4*idx);
      }
    }
    #pragma unroll
    for (int kk=0; kk<10; ++kk){
      bf16x8 a = *(const bf16x8*)(h_s + arow_h + 32*kk);
      if (kk & 1){
        acc0b = __builtin_amdgcn_mfma_f32_16x16x32_bf16(a, B1[0][kk], acc0b, 0,0,0);
        if (two) acc1b = __builtin_amdgcn_mfma_f32_16x16x32_bf16(a, B1[1][kk], acc1b, 0,0,0);
      } else {
        acc0a = __builtin_amdgcn_mfma_f32_16x16x32_bf16(a, B1[0][kk], acc0a, 0,0,0);
        if (two) acc1a = __builtin_amdgcn_mfma_f32_16x16x32_bf16(a, B1[1][kk], acc1a, 0,0,0);
      }
    }
    // -- write gate fragments to g_s (overlay on f_cur; f_cur reads all complete)
    {
      int nb = 16*tnb + (lane & 15);
      int mr = 16*tm + 4*(lane >> 4);
      f32x4 s0 = acc0a + acc0b;
      #pragma unroll
      for (int r4=0; r4<4; ++r4) g_s[(mr+r4)*52 + nb] = s0[r4];
      if (two){
        f32x4 s1 = acc1a + acc1b;
        #pragma unroll
        for (int r4=0; r4<4; ++r4) g_s[(mr+r4)*52 + nb + 16] = s1[r4];
      }
    }
    __syncthreads();   // B3: g_s ready
    // -- update + publish; then PER-WAVE drain + flag (no end barrier)
    if (tid < 384){
      int mt = (mask_s[m_u*8 + (t>>5)] >> (t&31)) & 1u;
      float4 ga = *(const float4*)(g_s + m_u*52 + 8*up);
      float4 gb = *(const float4*)(g_s + m_u*52 + 8*up + 4);
      {
        float gi = sigm (ga.x + bias_a.x);
        float gf = sigm (ga.y + bias_a.y);
        float gg = ftanh(ga.z + bias_a.z);
        float go = sigm (ga.w + bias_a.w);
        float cn = gf*c_a + gi*gg;
        float hn = go*ftanh(cn);
        if (mt){ c_a = cn; h_a = hn; }
      }
      {
        float gi = sigm (gb.x + bias_b.x);
        float gf = sigm (gb.y + bias_b.y);
        float gg = ftanh(gb.z + bias_b.z);
        float go = sigm (gb.w + bias_b.w);
        float cn = gf*c_b + gi*gg;
        float hn = go*ftanh(cn);
        if (mt){ c_b = cn; h_b = hn; }
      }
      unsigned pack = (unsigned)f2bf(h_a) | ((unsigned)f2bf(h_b) << 16);
      unsigned* hdst = hhd + (size_t)(dir*257 + s + 1)*SLOT_DW + m_u*ROW_DW + g*6 + up;
      __hip_atomic_store(hdst, pack, __ATOMIC_RELAXED, __HIP_MEMORY_SCOPE_AGENT);
    }
    asm volatile("s_waitcnt vmcnt(0)" ::: "memory");   // own publishes + feat DMA drained
    if (lane == 0)
      __hip_atomic_store(myflags + g*8 + w, s + 1, __ATOMIC_RELAXED, __HIP_MEMORY_SCOPE_AGENT);
  }
}

// ---------- 5. logits (fused both dirs + out_b), 32 seqs/block
__global__ __launch_bounds__(640) void k_logits(const unsigned int* __restrict__ hhd,
    const float* __restrict__ outW, const float* __restrict__ outb, float* __restrict__ lg){
  extern __shared__ char lsm[];
  float*    w_l = (float*)lsm;                    // [20][608] f32 = 48,640 B
  ushort_t* h_l = (ushort_t*)(lsm + 20*608*4);    // [32][608] bf16 = 38,912 B
  int tid = threadIdx.x;
  for (int idx=tid; idx<20*608; idx+=640){
    int tag = idx/608, k = idx - tag*608;
    w_l[idx] = (k < 600) ? outW[(size_t)tag*600 + k] : 0.f;
  }
  unsigned* hld = (unsigned*)h_l;
  int seq0 = blockIdx.x*32;
  for (int idx=tid; idx<32*304; idx+=640){        // 304 dwords/row (last 4 zeroed)
    int m = idx/304, d = idx - m*304;
    unsigned v = 0u;
    if (d < 300){
      int dir = d >= 150;
      int dd = d - dir*150;
      int seq = seq0 + m;
      int b = seq >> 8, t = seq & 255;
      int slot = dir ? (T_ - t) : (t + 1);
      v = hhd[(size_t)(dir*257 + slot)*SLOT_DW + b*ROW_DW + dd];
    }
    hld[m*304 + d] = v;
  }
  __syncthreads();
  int sq = tid/20, tag = tid - sq*20;
  const ushort_t* hr = h_l + sq*608;
  const float*    wr = w_l + tag*608;
  float acc = 0.f;
  #pragma unroll
  for (int jj=0; jj<152; ++jj){
    ushort4 h4 = *(const ushort4*)(hr + 4*jj);
    float4  wv = *(const float4*)(wr + 4*jj);
    acc += bf2f(h4.x)*wv.x + bf2f(h4.y)*wv.y + bf2f(h4.z)*wv.z + bf2f(h4.w)*wv.w;
  }
  lg[(size_t)(seq0+sq)*NTAG + tag] = acc + outb[tag];
}

// ---------- 6. CRF forward + gold score: register-resident, shfl alpha
__global__ __launch_bounds__(64) void k_crf(const float* __restrict__ lg,
    const float* __restrict__ tr, const int* __restrict__ word_x,
    const int* __restrict__ y, float* __restrict__ out){
  int b = blockIdx.x, lane = threadIdx.x;
  float trr[20];
  if (lane < NTAG){
    #pragma unroll
    for (int j=0;j<NTAG;++j) trr[j] = tr[lane*NTAG + j];
  }
  float tstop = (lane < NTAG) ? tr[STOP_*NTAG + lane] : NEG_;
  unsigned mbits = 0u;
  if (lane < 8){
    const int* wp = word_x + b*T_ + lane*32;
    #pragma unroll
    for (int j4=0; j4<8; ++j4){
      int4 v = *(const int4*)(wp + 4*j4);
      mbits |= (v.x>0 ? 1u:0u) << (4*j4);
      mbits |= (v.y>0 ? 1u:0u) << (4*j4+1);
      mbits |= (v.z>0 ? 1u:0u) << (4*j4+2);
      mbits |= (v.w>0 ? 1u:0u) << (4*j4+3);
    }
  }
  const float* lgb = lg + (size_t)b*T_*NTAG;
  float alpha = (lane == START_) ? 0.f : NEG_;
  float hv_cur = lgb[lane];
  #pragma unroll 1
  for (int t=0; t<T_; ++t){
    float hv_next = (t < T_-1) ? lgb[(size_t)(t+1)*NTAG + lane] : 0.f;
    unsigned mrow = __shfl(mbits, t >> 5);
    int mt = (mrow >> (t & 31)) & 1;
    float aj[20];
    #pragma unroll
    for (int j=0;j<NTAG;++j) aj[j] = __shfl(alpha, j) + trr[j];
    float mx = -3.4e38f;
    #pragma unroll
    for (int j=0;j<NTAG;++j) mx = fmaxf(mx, aj[j]);
    float ss = 0.f;
    #pragma unroll
    for (int j=0;j<NTAG;++j) ss += __expf(aj[j] - mx);
    float anew = __logf(ss) + mx + hv_cur;
    if (mt && lane < NTAG) alpha = anew;
    hv_cur = hv_next;
  }
  float val = alpha + tstop;
  float mx = -3.4e38f;
  #pragma unroll
  for (int j=0;j<NTAG;++j) mx = fmaxf(mx, __shfl(val, j));
  float ss = 0.f;
  #pragma unroll
  for (int j=0;j<NTAG;++j) ss += __expf(__shfl(val, j) - mx);
  float Z = __logf(ss) + mx;
  float sc = 0.f; int cnt = 0;
  #pragma unroll 1
  for (int qq=0;qq<4;++qq){
    int t = lane + 64*qq;
    if (word_x[b*T_ + t] > 0){
      int yt = y[b*T_ + t];
      int yp = (t == 0) ? START_ : y[b*T_ + t - 1];
      sc += lgb[(size_t)t*NTAG + yt] + tr[yt*NTAG + yp];
      cnt++;
    }
  }
  for (int off=32; off; off>>=1){
    sc += __shfl_down(sc, off);
    cnt += __shfl_down(cnt, off);
  }
  if (lane == 0){
    int last = y[b*T_ + cnt - 1];
    sc += tr[STOP_*NTAG + last];
    out[b] = Z - sc;
  }
}

extern "C" void kernel_launch(void* const* d_in, const int* in_sizes, int n_in,
                              void* d_out, int out_size, void* d_ws, size_t ws_size,
                              hipStream_t stream) {
  (void)in_sizes; (void)n_in; (void)out_size; (void)ws_size;
  const int*   word_x  = (const int*)  d_in[0];
  const int*   char_x  = (const int*)  d_in[1];
  const int*   y       = (const int*)  d_in[2];
  const float* wemb    = (const float*)d_in[3];
  const float* cemb    = (const float*)d_in[4];
  const float* cWih    = (const float*)d_in[5];
  const float* cWhh    = (const float*)d_in[6];
  const float* cbih    = (const float*)d_in[7];
  const float* cbhh    = (const float*)d_in[8];
  const float* fWih    = (const float*)d_in[9];
  const float* fWhh    = (const float*)d_in[10];
  const float* fbih    = (const float*)d_in[11];
  const float* fbhh    = (const float*)d_in[12];
  const float* bWih    = (const float*)d_in[13];
  const float* bWhh    = (const float*)d_in[14];
  const float* bbih    = (const float*)d_in[15];
  const float* bbhh    = (const float*)d_in[16];
  const float* outW    = (const float*)d_in[17];
  const float* outb    = (const float*)d_in[18];
  const float* trans   = (const float*)d_in[19];
  float* out = (float*)d_out;

  char* ws = (char*)d_ws;
  // layout (bytes, 256-aligned):
  float*        Ec_t   = (float*)       (ws + 0);          //   204,800
  ushort_t*     feat   = (ushort_t*)    (ws + 204800);     // 16384*416*2 = 13,631,488
  unsigned int* hh     = (unsigned int*)(ws + 13836288);   // HH_DW*4 = 21,579,776
  int*          flags  = (int*)         (ws + 35416064);   // 512 ints = 2048
  float*        lg     = (float*)       (ws + 35418112);   // 1,310,720 -> end 36,728,832

  static const int LDS_W = 41984 + 2*53248 + 2048;          // 150,528 B
  static const int LDS_C = 64*132*2 + 64*401*4;             // 119,552 B
  static const int LDS_L = 20*608*4 + 32*608*2;             //  87,552 B
  hipFuncSetAttribute((const void*)k_word2, hipFuncAttributeMaxDynamicSharedMemorySize, LDS_W);
  hipFuncSetAttribute((const void*)k_char,  hipFuncAttributeMaxDynamicSharedMemorySize, LDS_C);
  hipFuncSetAttribute((const void*)k_logits,hipFuncAttributeMaxDynamicSharedMemorySize, LDS_L);

  hipLaunchKernelGGL(k_prep, dim3(ZBLK + 200), dim3(256), 0, stream, hh, flags, cemb, cWih, cbih, cbhh, Ec_t);
  hipLaunchKernelGGL(k_feat, dim3(6656), dim3(256), 0, stream, word_x, wemb, feat);
  hipLaunchKernelGGL(k_char, dim3(256), dim3(256), LDS_C, stream, Ec_t, cWhh, char_x, feat);
  hipLaunchKernelGGL(k_word2, dim3(2*NW_), dim3(512), LDS_W, stream,
                     feat, hh, fWih, fWhh, fbih, fbhh, bWih, bWhh, bbih, bbhh, word_x, flags);
  hipLaunchKernelGGL(k_logits, dim3(NSEQ/32), dim3(640), LDS_L, stream, hh, outW, outb, lg);
  hipLaunchKernelGGL(k_crf, dim3(64), dim3(64), 0, stream, lg, trans, word_x, y, out);
}

// Round 18
// 1741.488 us; speedup vs baseline: 1.1639x; 1.1639x over previous
//
#include <hip/hip_runtime.h>

#define B_ 64
#define T_ 256
#define LC_ 16
#define CV_ 128
#define CE_ 100
#define WE_ 300
#define CH_ 100
#define WH_ 300
#define NTAG 20
#define START_ 18
#define STOP_ 19
#define NEG_ -10000.0f
#define NSEQ (B_*T_)          // 16384
#define KFP 416               // padded feat row (400 data + 16 zero)
#define NW_ 25                // workgroups per direction in k_word2
#define UH_ 12                // hidden units per workgroup (25*12=300)
#define ROW_DW 164            // dwords per batch row in hh (= h_s LDS row: 328 bf16)
#define SLOT_DW (64*ROW_DW)   // 10,496 dwords per slot
#define HH_DW (2*257*SLOT_DW) // 5,394,944 dwords total
#define ZBLK ((HH_DW + 64 + 255)/256)

typedef unsigned short ushort_t;
typedef __attribute__((ext_vector_type(8))) short bf16x8;
typedef __attribute__((ext_vector_type(4))) float f32x4;
union BF8 { bf16x8 v; ushort_t u[8]; };

__device__ inline float bf2f(ushort_t u){ return __uint_as_float(((unsigned int)u)<<16); }
__device__ inline ushort_t f2bf(float f){
  unsigned int x = __float_as_uint(f);
  unsigned int r = (x + 0x7fffu + ((x>>16)&1u)) >> 16;
  return (ushort_t)r;
}
__device__ inline float sigm(float x){ return 1.f/(1.f+__expf(-x)); }
__device__ inline float ftanh(float x){
  float ax = fabsf(x);
  float e = __expf(-2.f*ax);
  float t = (1.f-e)/(1.f+e);
  return copysignf(t, x);
}
// async global->LDS 16B DMA; aux=17 (SC0|SC1: cache-bypass, MALL-coherent) for h
__device__ inline void gload16_byp(const unsigned* g, unsigned* l){
  __builtin_amdgcn_global_load_lds((const __attribute__((address_space(1))) unsigned*)g,
                                   (__attribute__((address_space(3))) unsigned*)l, 16, 0, 17);
}
// cached variant for read-only feat
__device__ inline void gload16(const unsigned* g, unsigned* l){
  __builtin_amdgcn_global_load_lds((const __attribute__((address_space(1))) unsigned*)g,
                                   (__attribute__((address_space(3))) unsigned*)l, 16, 0, 0);
}

// ---------- 0. prep: [0..ZBLK) zero whole hh + flags; [ZBLK..+200) char gate table
__global__ __launch_bounds__(256) void k_prep(unsigned int* __restrict__ hh, int* __restrict__ flags,
    const float* __restrict__ cemb, const float* __restrict__ cWih,
    const float* __restrict__ cbih, const float* __restrict__ cbhh, float* __restrict__ Ec_t){
  int bid = blockIdx.x;
  if (bid < ZBLK){
    size_t idx = (size_t)bid*256 + threadIdx.x;
    if (idx < HH_DW) hh[idx] = 0u;
    else if (idx < HH_DW + 64) flags[idx - HH_DW] = 0;
  } else {
    int idx = (bid - ZBLK)*256 + threadIdx.x;    // 51200 = 400*128
    int r = idx >> 7, c = idx & 127;
    float a = cbih[r] + cbhh[r];
    for (int k=0;k<CE_;++k) a += cemb[c*CE_+k]*cWih[r*CE_+k];
    Ec_t[c*400 + r] = a;
  }
}

// ---------- 2. char LSTM (MFMA): 64 seqs/WG, 4 waves; writes h DIRECTLY into feat char cols
__global__ __launch_bounds__(256) void k_char(const float* __restrict__ Ec_t,
    const float* __restrict__ Whh, const int* __restrict__ char_x,
    ushort_t* __restrict__ feat){
  extern __shared__ char csm[];
  ushort_t* h_lds = (ushort_t*)csm;              // [64][132] bf16 = 16,896 B
  float*    g_lds = (float*)(csm + 64*132*2);    // [64][401] f32  = 102,656 B
  const int tid  = threadIdx.x;
  const int lane = tid & 63;
  const int w    = tid >> 6;                     // 4 waves
  const int tb   = w*6;                          // n-tile base (w3 also does tile 24)
  bf16x8 Bf[7][4];
  {
    int ntile = (w==3) ? 7 : 6;
    for (int tt=0; tt<ntile; ++tt){
      int r = (tb+tt)*16 + (lane & 15);
      #pragma unroll
      for (int ks=0; ks<4; ++ks){
        BF8 tmp;
        #pragma unroll
        for (int j=0; j<8; ++j){
          int k = 32*ks + 8*(lane>>4) + j;
          tmp.u[j] = (k < CH_) ? f2bf(Whh[(size_t)r*CH_ + k]) : (ushort_t)0;
        }
        Bf[tt][ks] = tmp.v;
      }
    }
  }
  for (int i=tid; i<64*132; i+=256) h_lds[i] = 0;
  const int seq_l = tid & 63;
  const int us    = tid >> 6;
  const int seqg  = blockIdx.x*64 + seq_l;
  const int u0    = us*25;
  float c_r[25], h_r[25];
  #pragma unroll
  for (int j=0;j<25;++j){ c_r[j]=0.f; h_r[j]=0.f; }
  const int* cx = char_x + (size_t)seqg*LC_;
  __syncthreads();
  #pragma unroll 1
  for (int t=0; t<LC_; ++t){
    #pragma unroll
    for (int m=0; m<4; ++m){
      int abase = (16*m + (lane&15))*132 + 8*(lane>>4);
      bf16x8 a0 = *(const bf16x8*)(h_lds + abase);
      bf16x8 a1 = *(const bf16x8*)(h_lds + abase + 32);
      bf16x8 a2 = *(const bf16x8*)(h_lds + abase + 64);
      bf16x8 a3 = *(const bf16x8*)(h_lds + abase + 96);
      int rw = 16*m + 4*(lane>>4);
      #pragma unroll
      for (int tt=0; tt<6; ++tt){
        f32x4 acc = {0,0,0,0};
        acc = __builtin_amdgcn_mfma_f32_16x16x32_bf16(a0, Bf[tt][0], acc, 0,0,0);
        acc = __builtin_amdgcn_mfma_f32_16x16x32_bf16(a1, Bf[tt][1], acc, 0,0,0);
        acc = __builtin_amdgcn_mfma_f32_16x16x32_bf16(a2, Bf[tt][2], acc, 0,0,0);
        acc = __builtin_amdgcn_mfma_f32_16x16x32_bf16(a3, Bf[tt][3], acc, 0,0,0);
        int col = (tb+tt)*16 + (lane&15);
        #pragma unroll
        for (int r4=0;r4<4;++r4) g_lds[(rw+r4)*401 + col] = acc[r4];
      }
      if (w == 3){
        f32x4 acc = {0,0,0,0};
        acc = __builtin_amdgcn_mfma_f32_16x16x32_bf16(a0, Bf[6][0], acc, 0,0,0);
        acc = __builtin_amdgcn_mfma_f32_16x16x32_bf16(a1, Bf[6][1], acc, 0,0,0);
        acc = __builtin_amdgcn_mfma_f32_16x16x32_bf16(a2, Bf[6][2], acc, 0,0,0);
        acc = __builtin_amdgcn_mfma_f32_16x16x32_bf16(a3, Bf[6][3], acc, 0,0,0);
        int col = 24*16 + (lane&15);
        #pragma unroll
        for (int r4=0;r4<4;++r4) g_lds[(rw+r4)*401 + col] = acc[r4];
      }
    }
    int ch = cx[t];
    __syncthreads();
    {
      const float* ec = Ec_t + (size_t)ch*400;
      const float* gr = g_lds + seq_l*401;
      #pragma unroll
      for (int j=0;j<25;++j){
        int u = u0 + j;
        float gi = gr[u        ] + ec[u        ];
        float gf = gr[100 + u  ] + ec[100 + u  ];
        float gg = gr[200 + u  ] + ec[200 + u  ];
        float go = gr[300 + u  ] + ec[300 + u  ];
        float I = sigm(gi), F = sigm(gf), G = ftanh(gg), O = sigm(go);
        float cn = F*c_r[j] + I*G;
        float hn = O*ftanh(cn);
        if (ch > 0){ c_r[j] = cn; h_r[j] = hn; }
        h_lds[seq_l*132 + u] = f2bf(h_r[j]);
      }
    }
    __syncthreads();
  }
  {
    int bb = seqg >> 8, tt2 = seqg & 255;
    ushort_t* dst = feat + (size_t)(tt2*64 + bb)*KFP + WE_ + u0;
    #pragma unroll
    for (int j=0;j<25;++j) dst[j] = f2bf(h_r[j]);
  }
}

// ---------- 3. feat builder: cols 0..299 = wemb[word_x]; cols 300..415 zeroed
__global__ __launch_bounds__(256) void k_feat(const int* __restrict__ word_x,
    const float* __restrict__ wemb, ushort_t* __restrict__ feat){
  int gid = blockIdx.x*256 + threadIdx.x;      // 16384*104 groups of 4 cols
  int rf = gid / 104;                          // rf = t*64 + b
  int j4 = gid - rf*104;
  int k = 4*j4;
  int t = rf >> 6, b = rf & 63;
  ushort4 u = make_ushort4(0,0,0,0);
  if (k < WE_){
    int seq = b*T_ + t;
    int wid = word_x[seq];
    float4 v = *(const float4*)&wemb[(size_t)wid*WE_ + k];
    u.x=f2bf(v.x); u.y=f2bf(v.y); u.z=f2bf(v.z); u.w=f2bf(v.w);
  }
  *(ushort4*)&feat[(size_t)rf*KFP + k] = u;
}

// ---------- 4. word LSTM: r16 structure verbatim (fastest measured: 1340 us)
__global__ __launch_bounds__(512, 2) void k_word2(
    const ushort_t* __restrict__ feat, unsigned int* __restrict__ hhd,
    const float* __restrict__ fWih, const float* __restrict__ fWhh,
    const float* __restrict__ fbih, const float* __restrict__ fbhh,
    const float* __restrict__ bWih, const float* __restrict__ bWhh,
    const float* __restrict__ bbih, const float* __restrict__ bbhh,
    const int* __restrict__ word_x, int* __restrict__ flags){
  extern __shared__ char smem[];
  ushort_t* h_s    = (ushort_t*)smem;                          // [64][328] = 41,984 B
  ushort_t* f_sb0  = (ushort_t*)(smem + 41984);                // [64][416] = 53,248 B
  ushort_t* f_sb1  = (ushort_t*)(smem + 41984 + 53248);        // [64][416] = 53,248 B
  unsigned* mask_s = (unsigned*)(smem + 41984 + 106496);       // [64][8]   =  2,048 B
  const int tid  = threadIdx.x;
  const int lane = tid & 63;
  const int w    = tid >> 6;         // 8 waves
  const int dir  = blockIdx.x & 1;
  const int g    = blockIdx.x >> 1;  // 0..24
  const int u0   = g * UH_;
  const int tm   = w & 3;            // m-tile (batch 16-row group)
  const int grp  = w >> 2;           // 0: n-tiles {0,1}; 1: n-tile {2}
  const bool two = (grp == 0);
  const int tnb  = grp ? 2 : 0;
  const float* Wih = dir ? bWih : fWih;
  const float* Whh = dir ? bWhh : fWhh;
  const float* bi  = dir ? bbih : fbih;
  const float* bh  = dir ? bbhh : fbhh;
  int* myflags = flags + dir*32;

  // ---- persistent B fragments (W_ih: 13 k-slabs; W_hh: 10 k-slabs)
  bf16x8 B2[2][13], B1[2][10];
  {
    const int kb = 8*(lane >> 4);
    #pragma unroll
    for (int ti=0; ti<2; ++ti){
      if (ti == 0 || two){
        int nl = 16*(tnb+ti) + (lane & 15);
        int r  = (nl & 3)*WH_ + u0 + (nl >> 2);   // gate q*300 + unit
        #pragma unroll
        for (int kk=0; kk<13; ++kk){
          BF8 tmp;
          #pragma unroll
          for (int j=0; j<8; ++j){
            int k = 32*kk + kb + j;
            tmp.u[j] = (k < 400) ? f2bf(Wih[(size_t)r*400 + k]) : (ushort_t)0;
          }
          B2[ti][kk] = tmp.v;
        }
        #pragma unroll
        for (int kk=0; kk<10; ++kk){
          BF8 tmp;
          #pragma unroll
          for (int j=0; j<8; ++j){
            int k = 32*kk + kb + j;
            tmp.u[j] = (k < WH_) ? f2bf(Whh[(size_t)r*WH_ + k]) : (ushort_t)0;
          }
          B1[ti][kk] = tmp.v;
        }
      }
    }
  }
  // ---- build word-mask bitmap: mask_s[b][t>>5] bit (t&31)
  if (tid < 512){
    int row = tid >> 3, dw = tid & 7;
    const int* wp = word_x + row*T_ + dw*32;
    unsigned bits = 0u;
    #pragma unroll
    for (int j4=0; j4<8; ++j4){
      int4 v = *(const int4*)(wp + 4*j4);
      bits |= (v.x>0 ? 1u:0u) << (4*j4);
      bits |= (v.y>0 ? 1u:0u) << (4*j4+1);
      bits |= (v.z>0 ? 1u:0u) << (4*j4+2);
      bits |= (v.w>0 ? 1u:0u) << (4*j4+3);
    }
    mask_s[row*8 + dw] = bits;
  }

  // ---- update threads: tid<384: m_u = tid&63, up = tid>>6 (units u0+2up, u0+2up+1)
  const int m_u = tid & 63;
  const int up  = tid >> 6;          // 0..5 for update threads
  float4 bias_a = {0,0,0,0}, bias_b = {0,0,0,0};
  if (tid < 384){
    int u = u0 + 2*up;
    bias_a.x = bi[0*WH_+u] + bh[0*WH_+u];
    bias_a.y = bi[1*WH_+u] + bh[1*WH_+u];
    bias_a.z = bi[2*WH_+u] + bh[2*WH_+u];
    bias_a.w = bi[3*WH_+u] + bh[3*WH_+u];
    bias_b.x = bi[0*WH_+u+1] + bh[0*WH_+u+1];
    bias_b.y = bi[1*WH_+u+1] + bh[1*WH_+u+1];
    bias_b.z = bi[2*WH_+u+1] + bh[2*WH_+u+1];
    bias_b.w = bi[3*WH_+u+1] + bh[3*WH_+u+1];
  }
  float c_a=0.f, h_a=0.f, c_b=0.f, h_b=0.f;
  const int arow_f = (16*tm + (lane&15))*KFP + 8*(lane>>4);
  const int arow_h = (16*tm + (lane&15))*328 + 8*(lane>>4);
  unsigned* h_sd = (unsigned*)h_s;

  // ---- prologue: DMA feat(first t) into buffer 0 (3328 x 16B)
  {
    int t0 = dir ? (T_-1) : 0;
    const unsigned* fsrc = (const unsigned*)(feat + (size_t)t0*64*KFP);
    unsigned* fdl = (unsigned*)f_sb0;
    #pragma unroll
    for (int i=0;i<7;++i){
      int idx = tid + 512*i;
      if (i < 6 || idx < 3328) gload16(fsrc + 4*idx, fdl + 4*idx);
    }
  }
  asm volatile("s_waitcnt vmcnt(0)" ::: "memory");
  __syncthreads();

  #pragma unroll 1
  for (int s=0; s<T_; ++s){
    int t = dir ? (T_-1-s) : s;
    const ushort_t* f_cur = (s & 1) ? f_sb1 : f_sb0;
    float* g_s = (float*)f_cur;          // overlay: valid after all f_cur MFMA reads
    // -- wait until all WGs of this dir published slot s
    if (w == 0 && s > 0){
      bool act = lane < NW_;
      for (int it=0; it<2000000; ++it){
        int f = act ? __hip_atomic_load(myflags + lane, __ATOMIC_RELAXED, __HIP_MEMORY_SCOPE_AGENT)
                    : 0x7fffffff;
        if (__all(f >= s)) break;
        __builtin_amdgcn_s_sleep(1);
      }
    }
    __syncthreads();
    // -- issue async h(s) DMA: 2624 x 16B (global layout == LDS layout, pads zero)
    {
      const unsigned* hsrc = hhd + (size_t)(dir*257 + s)*SLOT_DW;
      #pragma unroll
      for (int i=0;i<6;++i){
        int idx = tid + 512*i;
        if (i < 5 || idx < 2624) gload16_byp(hsrc + 4*idx, h_sd + 4*idx);
      }
    }
    // -- feat MFMAs overlap the h DMA
    f32x4 acc0a = {0,0,0,0}, acc0b = {0,0,0,0}, acc1a = {0,0,0,0}, acc1b = {0,0,0,0};
    #pragma unroll
    for (int kk=0; kk<13; ++kk){
      bf16x8 a = *(const bf16x8*)(f_cur + arow_f + 32*kk);
      if (kk & 1){
        acc0b = __builtin_amdgcn_mfma_f32_16x16x32_bf16(a, B2[0][kk], acc0b, 0,0,0);
        if (two) acc1b = __builtin_amdgcn_mfma_f32_16x16x32_bf16(a, B2[1][kk], acc1b, 0,0,0);
      } else {
        acc0a = __builtin_amdgcn_mfma_f32_16x16x32_bf16(a, B2[0][kk], acc0a, 0,0,0);
        if (two) acc1a = __builtin_amdgcn_mfma_f32_16x16x32_bf16(a, B2[1][kk], acc1a, 0,0,0);
      }
    }
    asm volatile("s_waitcnt vmcnt(0)" ::: "memory");   // h DMA landed (this wave)
    __syncthreads();                                    // all waves: f_cur reads + h DMA done
    // -- issue feat(s+1) DMA into the other buffer (drained by end-of-step vmcnt)
    if (s + 1 < T_){
      int tn = dir ? (T_-2-s) : (s+1);
      const unsigned* fsrc = (const unsigned*)(feat + (size_t)tn*64*KFP);
      unsigned* fdl = (unsigned*)((s & 1) ? f_sb0 : f_sb1);
      #pragma unroll
      for (int i=0;i<7;++i){
        int idx = tid + 512*i;
        if (i < 6 || idx < 3328) gload16(fsrc + 4*idx, fdl + 4*idx);
      }
    }
    #pragma unroll
    for (int kk=0; kk<10; ++kk){
      bf16x8 a = *(const bf16x8*)(h_s + arow_h + 32*kk);
      if (kk & 1){
        acc0b = __builtin_amdgcn_mfma_f32_16x16x32_bf16(a, B1[0][kk], acc0b, 0,0,0);
        if (two) acc1b = __builtin_amdgcn_mfma_f32_16x16x32_bf16(a, B1[1][kk], acc1b, 0,0,0);
      } else {
        acc0a = __builtin_amdgcn_mfma_f32_16x16x32_bf16(a, B1[0][kk], acc0a, 0,0,0);
        if (two) acc1a = __builtin_amdgcn_mfma_f32_16x16x32_bf16(a, B1[1][kk], acc1a, 0,0,0);
      }
    }
    // -- write gate fragments to g_s (overlay on f_cur; f_cur reads all complete)
    {
      int nb = 16*tnb + (lane & 15);
      int mr = 16*tm + 4*(lane >> 4);
      f32x4 s0 = acc0a + acc0b;
      #pragma unroll
      for (int r4=0; r4<4; ++r4) g_s[(mr+r4)*52 + nb] = s0[r4];
      if (two){
        f32x4 s1 = acc1a + acc1b;
        #pragma unroll
        for (int r4=0; r4<4; ++r4) g_s[(mr+r4)*52 + nb + 16] = s1[r4];
      }
    }
    __syncthreads();
    // -- elementwise LSTM update + publish carried h (row-major slot, agent stores)
    if (tid < 384){
      int mt = (mask_s[m_u*8 + (t>>5)] >> (t&31)) & 1u;
      float4 ga = *(const float4*)(g_s + m_u*52 + 8*up);
      float4 gb = *(const float4*)(g_s + m_u*52 + 8*up + 4);
      {
        float gi = sigm (ga.x + bias_a.x);
        float gf = sigm (ga.y + bias_a.y);
        float gg = ftanh(ga.z + bias_a.z);
        float go = sigm (ga.w + bias_a.w);
        float cn = gf*c_a + gi*gg;
        float hn = go*ftanh(cn);
        if (mt){ c_a = cn; h_a = hn; }
      }
      {
        float gi = sigm (gb.x + bias_b.x);
        float gf = sigm (gb.y + bias_b.y);
        float gg = ftanh(gb.z + bias_b.z);
        float go = sigm (gb.w + bias_b.w);
        float cn = gf*c_b + gi*gg;
        float hn = go*ftanh(cn);
        if (mt){ c_b = cn; h_b = hn; }
      }
      unsigned pack = (unsigned)f2bf(h_a) | ((unsigned)f2bf(h_b) << 16);
      unsigned* hdst = hhd + (size_t)(dir*257 + s + 1)*SLOT_DW + m_u*ROW_DW + g*6 + up;
      __hip_atomic_store(hdst, pack, __ATOMIC_RELAXED, __HIP_MEMORY_SCOPE_AGENT);
    }
    asm volatile("s_waitcnt vmcnt(0)" ::: "memory");   // publishes + feat DMA drained
    __syncthreads();
    if (tid == 0)
      __hip_atomic_store(myflags + g, s + 1, __ATOMIC_RELAXED, __HIP_MEMORY_SCOPE_AGENT);
  }
}

// ---------- 5. logits (fused both dirs + out_b), 32 seqs/block
__global__ __launch_bounds__(640) void k_logits(const unsigned int* __restrict__ hhd,
    const float* __restrict__ outW, const float* __restrict__ outb, float* __restrict__ lg){
  extern __shared__ char lsm[];
  float*    w_l = (float*)lsm;                    // [20][608] f32 = 48,640 B
  ushort_t* h_l = (ushort_t*)(lsm + 20*608*4);    // [32][608] bf16 = 38,912 B
  int tid = threadIdx.x;
  for (int idx=tid; idx<20*608; idx+=640){
    int tag = idx/608, k = idx - tag*608;
    w_l[idx] = (k < 600) ? outW[(size_t)tag*600 + k] : 0.f;
  }
  unsigned* hld = (unsigned*)h_l;
  int seq0 = blockIdx.x*32;
  for (int idx=tid; idx<32*304; idx+=640){        // 304 dwords/row (last 4 zeroed)
    int m = idx/304, d = idx - m*304;
    unsigned v = 0u;
    if (d < 300){
      int dir = d >= 150;
      int dd = d - dir*150;
      int seq = seq0 + m;
      int b = seq >> 8, t = seq & 255;
      int slot = dir ? (T_ - t) : (t + 1);
      v = hhd[(size_t)(dir*257 + slot)*SLOT_DW + b*ROW_DW + dd];
    }
    hld[m*304 + d] = v;
  }
  __syncthreads();
  int sq = tid/20, tag = tid - sq*20;
  const ushort_t* hr = h_l + sq*608;
  const float*    wr = w_l + tag*608;
  float acc = 0.f;
  #pragma unroll
  for (int jj=0; jj<152; ++jj){
    ushort4 h4 = *(const ushort4*)(hr + 4*jj);
    float4  wv = *(const float4*)(wr + 4*jj);
    acc += bf2f(h4.x)*wv.x + bf2f(h4.y)*wv.y + bf2f(h4.z)*wv.z + bf2f(h4.w)*wv.w;
  }
  lg[(size_t)(seq0+sq)*NTAG + tag] = acc + outb[tag];
}

// ---------- 6. CRF forward + gold score: register-resident, shfl alpha
__global__ __launch_bounds__(64) void k_crf(const float* __restrict__ lg,
    const float* __restrict__ tr, const int* __restrict__ word_x,
    const int* __restrict__ y, float* __restrict__ out){
  int b = blockIdx.x, lane = threadIdx.x;
  float trr[20];
  if (lane < NTAG){
    #pragma unroll
    for (int j=0;j<NTAG;++j) trr[j] = tr[lane*NTAG + j];
  }
  float tstop = (lane < NTAG) ? tr[STOP_*NTAG + lane] : NEG_;
  unsigned mbits = 0u;
  if (lane < 8){
    const int* wp = word_x + b*T_ + lane*32;
    #pragma unroll
    for (int j4=0; j4<8; ++j4){
      int4 v = *(const int4*)(wp + 4*j4);
      mbits |= (v.x>0 ? 1u:0u) << (4*j4);
      mbits |= (v.y>0 ? 1u:0u) << (4*j4+1);
      mbits |= (v.z>0 ? 1u:0u) << (4*j4+2);
      mbits |= (v.w>0 ? 1u:0u) << (4*j4+3);
    }
  }
  const float* lgb = lg + (size_t)b*T_*NTAG;
  float alpha = (lane == START_) ? 0.f : NEG_;
  float hv_cur = lgb[lane];
  #pragma unroll 1
  for (int t=0; t<T_; ++t){
    float hv_next = (t < T_-1) ? lgb[(size_t)(t+1)*NTAG + lane] : 0.f;
    unsigned mrow = __shfl(mbits, t >> 5);
    int mt = (mrow >> (t & 31)) & 1;
    float aj[20];
    #pragma unroll
    for (int j=0;j<NTAG;++j) aj[j] = __shfl(alpha, j) + trr[j];
    float mx = -3.4e38f;
    #pragma unroll
    for (int j=0;j<NTAG;++j) mx = fmaxf(mx, aj[j]);
    float ss = 0.f;
    #pragma unroll
    for (int j=0;j<NTAG;++j) ss += __expf(aj[j] - mx);
    float anew = __logf(ss) + mx + hv_cur;
    if (mt && lane < NTAG) alpha = anew;
    hv_cur = hv_next;
  }
  float val = alpha + tstop;
  float mx = -3.4e38f;
  #pragma unroll
  for (int j=0;j<NTAG;++j) mx = fmaxf(mx, __shfl(val, j));
  float ss = 0.f;
  #pragma unroll
  for (int j=0;j<NTAG;++j) ss += __expf(__shfl(val, j) - mx);
  float Z = __logf(ss) + mx;
  float sc = 0.f; int cnt = 0;
  #pragma unroll 1
  for (int qq=0;qq<4;++qq){
    int t = lane + 64*qq;
    if (word_x[b*T_ + t] > 0){
      int yt = y[b*T_ + t];
      int yp = (t == 0) ? START_ : y[b*T_ + t - 1];
      sc += lgb[(size_t)t*NTAG + yt] + tr[yt*NTAG + yp];
      cnt++;
    }
  }
  for (int off=32; off; off>>=1){
    sc += __shfl_down(sc, off);
    cnt += __shfl_down(cnt, off);
  }
  if (lane == 0){
    int last = y[b*T_ + cnt - 1];
    sc += tr[STOP_*NTAG + last];
    out[b] = Z - sc;
  }
}

extern "C" void kernel_launch(void* const* d_in, const int* in_sizes, int n_in,
                              void* d_out, int out_size, void* d_ws, size_t ws_size,
                              hipStream_t stream) {
  (void)in_sizes; (void)n_in; (void)out_size; (void)ws_size;
  const int*   word_x  = (const int*)  d_in[0];
  const int*   char_x  = (const int*)  d_in[1];
  const int*   y       = (const int*)  d_in[2];
  const float* wemb    = (const float*)d_in[3];
  const float* cemb    = (const float*)d_in[4];
  const float* cWih    = (const float*)d_in[5];
  const float* cWhh    = (const float*)d_in[6];
  const float* cbih    = (const float*)d_in[7];
  const float* cbhh    = (const float*)d_in[8];
  const float* fWih    = (const float*)d_in[9];
  const float* fWhh    = (const float*)d_in[10];
  const float* fbih    = (const float*)d_in[11];
  const float* fbhh    = (const float*)d_in[12];
  const float* bWih    = (const float*)d_in[13];
  const float* bWhh    = (const float*)d_in[14];
  const float* bbih    = (const float*)d_in[15];
  const float* bbhh    = (const float*)d_in[16];
  const float* outW    = (const float*)d_in[17];
  const float* outb    = (const float*)d_in[18];
  const float* trans   = (const float*)d_in[19];
  float* out = (float*)d_out;

  char* ws = (char*)d_ws;
  // layout (bytes, 256-aligned):
  float*        Ec_t   = (float*)       (ws + 0);          //   204,800
  ushort_t*     feat   = (ushort_t*)    (ws + 204800);     // 16384*416*2 = 13,631,488
  unsigned int* hh     = (unsigned int*)(ws + 13836288);   // HH_DW*4 = 21,579,776
  int*          flags  = (int*)         (ws + 35416064);   // 64 ints = 256
  float*        lg     = (float*)       (ws + 35416320);   // 1,310,720 -> end 36,727,040

  static const int LDS_W = 41984 + 2*53248 + 2048;          // 150,528 B
  static const int LDS_C = 64*132*2 + 64*401*4;             // 119,552 B
  static const int LDS_L = 20*608*4 + 32*608*2;             //  87,552 B
  hipFuncSetAttribute((const void*)k_word2, hipFuncAttributeMaxDynamicSharedMemorySize, LDS_W);
  hipFuncSetAttribute((const void*)k_char,  hipFuncAttributeMaxDynamicSharedMemorySize, LDS_C);
  hipFuncSetAttribute((const void*)k_logits,hipFuncAttributeMaxDynamicSharedMemorySize, LDS_L);

  hipLaunchKernelGGL(k_prep, dim3(ZBLK + 200), dim3(256), 0, stream, hh, flags, cemb, cWih, cbih, cbhh, Ec_t);
  hipLaunchKernelGGL(k_feat, dim3(6656), dim3(256), 0, stream, word_x, wemb, feat);
  hipLaunchKernelGGL(k_char, dim3(256), dim3(256), LDS_C, stream, Ec_t, cWhh, char_x, feat);
  hipLaunchKernelGGL(k_word2, dim3(2*NW_), dim3(512), LDS_W, stream,
                     feat, hh, fWih, fWhh, fbih, fbhh, bWih, bWhh, bbih, bbhh, word_x, flags);
  hipLaunchKernelGGL(k_logits, dim3(NSEQ/32), dim3(640), LDS_L, stream, hh, outW, outb, lg);
  hipLaunchKernelGGL(k_crf, dim3(64), dim3(64), 0, stream, lg, trans, word_x, y, out);
}